// Round 13
// baseline (42.867 us; speedup 1.0000x reference)
//
#include <hip/hip_runtime.h>

// ---------------------------------------------------------------------------
// ConvBlock: y = clip(BN(tr(conv3x3(x^2, Wconv))), -1, 1)
// Wconv[oc][c][di][dj] = weight[oc>>3][(c*9+3di+dj)>>3][(oc-(c*9+3di+dj))&7]
// GEMM: A = Wconv (M=64 oc), B = im2col(x^2) (N=65536 px), K=576.
// bf16 MFMA 32x32x16, 3-pass hi/lo split.
// Round 13: MERGE-FREE. Wave = one full-K output row (wmt x py), 2-row tiles,
// 256-thr blocks, 4 blocks/CU (16 waves/CU). 3 barriers. Per-(dj,ks-pair)
// weight hoisting for ILP. Conflict-free staging. De-fused pipeline.
// ---------------------------------------------------------------------------

#define A_MORR 0.8578f
#define R_MORR 0.8578f
#define TR_C1 (A_MORR * A_MORR + R_MORR * R_MORR)
#define TR_C2 (-2.0f * A_MORR * R_MORR)
#define TR_C3 (1.0f + (A_MORR * R_MORR) * (A_MORR * R_MORR))
#define BN_EPS 1e-5f

#define NPIX 65536
#define X2_LO 17408          // 4*34*128: lo plane offset
#define SMEM_BYTES 34816
#define NBLK 1024            // conv grid size (16 x 64)

typedef __attribute__((ext_vector_type(8))) short bf16x8;
typedef __attribute__((ext_vector_type(16))) float f32x16;

__device__ __forceinline__ void bf16split(float s, unsigned short& h, unsigned short& l) {
    union { float f; unsigned u; } cv; cv.f = s;
    unsigned r = (cv.u + 0x7fffu + ((cv.u >> 16) & 1u)) & 0xffff0000u;
    h = (unsigned short)(r >> 16);
    union { unsigned u; float f; } hv; hv.u = r;
    float lo = s - hv.f;
    cv.f = lo;
    unsigned r2 = cv.u + 0x7fffu + ((cv.u >> 16) & 1u);
    l = (unsigned short)(r2 >> 16);
}

// ---------------------------------------------------------------------------
// Kernel A: fragment-ready bf16 hi/lo weights.
// wfrag[off*8 + ks*2 + mt][prec][lane][8ch] : 72 * 2048 B
// ---------------------------------------------------------------------------
__global__ __launch_bounds__(256) void prep_kernel(const float* __restrict__ w,
                                                   char* __restrict__ wfrag) {
    int gtid = blockIdx.x * 256 + threadIdx.x;
    if (gtid < 36864) {
        int j    = gtid & 7;
        int lane = (gtid >> 3) & 63;
        int okm  = gtid >> 9;
        int mt   = okm & 1;
        int ks   = (okm >> 1) & 3;
        int off  = okm >> 3;
        int oc   = mt * 32 + (lane & 31);
        int c    = ks * 16 + (lane >> 5) * 8 + j;
        int kg   = c * 9 + off;
        float val = w[(oc >> 3) * 576 + (kg >> 3) * 8 + ((oc - kg) & 7)];
        unsigned short h, l;
        bf16split(val, h, l);
        ((unsigned short*)(wfrag + okm * 2048))[lane * 8 + j] = h;
        ((unsigned short*)(wfrag + okm * 2048 + 1024))[lane * 8 + j] = l;
    }
}

// ---------------------------------------------------------------------------
// Kernel B: merge-free MFMA conv + tr; per-block BN partials.
// grid (16,64) = 1024 blocks, block 256 (4 waves: wmt x py), 4 blocks/CU.
// Block tile: 64 oc x 64 px (rows rt*2, rt*2+1). Wave (wmt,py): 32 oc x
// 32 px (row rt*2+py), FULL K=576 -> no merge. Uses staged rows py..py+2.
// LDS x2: [4 rows][34 cols][64 ch] bf16 hi+lo, granule swizzle g = q^(c&7):
//   byte(r,c,ch) = ((r*34+c)<<7) + (((ch>>3)^(c&7))<<4) + (ch&7)*2  (+X2_LO lo)
// Staging: thread owns one granule (8ch x 1col) -> ds_write_b128 conflict-free.
// ---------------------------------------------------------------------------
__global__ __launch_bounds__(256, 4) void conv_kernel(const float* __restrict__ x,
                                                      const char* __restrict__ wfrag,
                                                      float* __restrict__ out,
                                                      float* __restrict__ partials) {
    const int rt  = blockIdx.x;          // 2-row tile 0..15
    const int b   = blockIdx.y;
    const int bid = b * 16 + rt;         // 0..1023
    const int tid = threadIdx.x;

    const int lane = tid & 63;
    const int wv   = tid >> 6;           // 0..3
    const int wmt  = wv & 1;             // oc half
    const int py   = wv >> 1;            // owned row (0/1)
    const int col  = lane & 31;
    const int hs   = lane >> 5;

    __shared__ __align__(16) char smem[SMEM_BYTES];

    // ---- zero halo cols (c=0, c=33) ----
    if (tid < 128) {
        int pr = tid & 1;
        int q  = (tid >> 1) & 7;
        int rc = tid >> 4;               // 0..7
        int r  = rc >> 1;
        int cc = (rc & 1) ? 33 : 0;
        int g  = q ^ (cc & 7);
        *(uint4*)(smem + pr * X2_LO + ((r * 34 + cc) << 7) + (g << 4)) = uint4{0, 0, 0, 0};
    }

    // ---- stage x^2 hi/lo: thread = (col, ch-octet), rows rt*2-1..rt*2+2 ----
    {
        const int co = tid & 31;
        const int qg = tid >> 5;
        const int c  = 1 + co;
        const int gw = (qg ^ (c & 7)) << 4;
        const float* xb = x + (size_t)(b * 64 + qg * 8) * 1024 + co;
#pragma unroll
        for (int r = 0; r < 4; ++r) {
            int gr = rt * 2 - 1 + r;
            float v[8];
#pragma unroll
            for (int j = 0; j < 8; ++j) v[j] = 0.0f;
            if (gr >= 0 && gr < 32) {
#pragma unroll
                for (int j = 0; j < 8; ++j) v[j] = xb[j * 1024 + gr * 32];
            }
            unsigned hp[4], lp[4];
#pragma unroll
            for (int p = 0; p < 4; ++p) {
                unsigned short h0, l0, h1, l1;
                float s0 = v[2 * p] * v[2 * p];
                float s1 = v[2 * p + 1] * v[2 * p + 1];
                bf16split(s0, h0, l0);
                bf16split(s1, h1, l1);
                hp[p] = (unsigned)h0 | ((unsigned)h1 << 16);
                lp[p] = (unsigned)l0 | ((unsigned)l1 << 16);
            }
            char* dst = smem + ((r * 34 + c) << 7) + gw;
            *(uint4*)dst            = uint4{hp[0], hp[1], hp[2], hp[3]};
            *(uint4*)(dst + X2_LO)  = uint4{lp[0], lp[1], lp[2], lp[3]};
        }
    }
    __syncthreads();                     // BAR1: x2 ready

    // ---- K loop: FULL K per wave. dj x ks-pair (w hoisted) x ksi x di ----
    f32x16 acc;
#pragma unroll
    for (int i = 0; i < 16; ++i) acc[i] = 0.f;

    const char* wbase = wfrag + wmt * 2048 + (size_t)lane * 16;

#pragma unroll
    for (int dj = 0; dj < 3; ++dj) {
        const int c2 = col + dj;
        const int c7 = c2 & 7;
#pragma unroll
        for (int kp = 0; kp < 2; ++kp) {
            // hoist 12 weight frags (2 ks x 3 di x hi/lo) -> 48 VGPR window
            bf16x8 wh_[2][3], wl_[2][3];
#pragma unroll
            for (int ksi = 0; ksi < 2; ++ksi) {
#pragma unroll
                for (int di = 0; di < 3; ++di) {
                    const char* wp = wbase + (di * 3 + dj) * 16384 + (kp * 2 + ksi) * 4096;
                    wh_[ksi][di] = *(const bf16x8*)wp;
                    wl_[ksi][di] = *(const bf16x8*)(wp + 1024);
                }
            }
#pragma unroll
            for (int ksi = 0; ksi < 2; ++ksi) {
                const int ks = kp * 2 + ksi;
                const int gg = ((ks * 2 + hs) ^ c7) << 4;
                bf16x8 bh[3], bl[3];
#pragma unroll
                for (int di = 0; di < 3; ++di) {
                    const char* sp = smem + (((py + di) * 34 + c2) << 7) + gg;
                    bh[di] = *(const bf16x8*)sp;
                    bl[di] = *(const bf16x8*)(sp + X2_LO);
                }
#pragma unroll
                for (int di = 0; di < 3; ++di) {
                    acc = __builtin_amdgcn_mfma_f32_32x32x16_bf16(wh_[ksi][di], bh[di], acc, 0, 0, 0);
                    acc = __builtin_amdgcn_mfma_f32_32x32x16_bf16(wh_[ksi][di], bl[di], acc, 0, 0, 0);
                    acc = __builtin_amdgcn_mfma_f32_32x32x16_bf16(wl_[ksi][di], bh[di], acc, 0, 0, 0);
                }
            }
        }
    }

    // ---- tr + raw store (row rt*2+py) ----
    float tv[16];
    {
        const size_t obase = ((size_t)b * 64 + wmt * 32) * 1024 + (rt * 2 + py) * 32 + col;
#pragma unroll
        for (int j = 0; j < 16; ++j) {
            float cp = __cosf(acc[j]);
            float t  = fmaf(TR_C2, cp, TR_C1) / fmaf(TR_C2, cp, TR_C3);
            tv[j] = t;
            int ocl = (j & 3) + 8 * (j >> 2) + 4 * hs;
            out[obase + (size_t)ocl * 1024] = t;
        }
    }

    // ---- per-channel partials: red[64][66] (reuse x2 LDS) ----
    float* red1 = (float*)smem;                    // [64][66]
    float* red2 = red1 + 64 * 66;                  // [64][66]
    __syncthreads();                     // BAR2: x2 reads done
#pragma unroll
    for (int j = 0; j < 16; ++j) {
        int ocl = (j & 3) + 8 * (j >> 2) + 4 * hs;
        int ri  = (wmt * 32 + ocl) * 66 + py * 33 + col;
        red1[ri] = tv[j];
        red2[ri] = tv[j] * tv[j];
    }
    __syncthreads();                     // BAR3
    if (tid < 64) {
        float s1 = 0.f, s2 = 0.f;
#pragma unroll
        for (int k = 0; k < 64; ++k) {
            int idx = tid * 66 + (k >> 5) * 33 + (k & 31);
            s1 += red1[idx];
            s2 += red2[idx];
        }
        partials[(size_t)tid * NBLK + bid]        = s1;
        partials[(size_t)(64 + tid) * NBLK + bid] = s2;
    }
}

// ---------------------------------------------------------------------------
// Kernel C: reduce per-block partials -> BN scale/shift. grid 64, block 512.
// ---------------------------------------------------------------------------
__global__ __launch_bounds__(512) void stats_kernel(const float* __restrict__ partials,
                                                    const float* __restrict__ gamma,
                                                    const float* __restrict__ beta,
                                                    float* __restrict__ ss) {
    const int c   = blockIdx.x;          // channel 0..63
    const int tid = threadIdx.x;
    __shared__ float r1[512], r2[512];
    r1[tid] = partials[(size_t)c * NBLK + tid] + partials[(size_t)c * NBLK + 512 + tid];
    r2[tid] = partials[(size_t)(64 + c) * NBLK + tid]
            + partials[(size_t)(64 + c) * NBLK + 512 + tid];
    __syncthreads();
#pragma unroll
    for (int s = 256; s > 0; s >>= 1) {
        if (tid < s) {
            r1[tid] += r1[tid + s];
            r2[tid] += r2[tid + s];
        }
        __syncthreads();
    }
    if (tid == 0) {
        const float invN = 1.0f / (float)NPIX;
        float mean = r1[0] * invN;
        float var  = r2[0] * invN - mean * mean;
        float sc   = gamma[c] * rsqrtf(var + BN_EPS);
        ss[c]      = sc;
        ss[64 + c] = beta[c] - mean * sc;
    }
}

// ---------------------------------------------------------------------------
// Kernel D: in-place normalize + clip (float4)
// ---------------------------------------------------------------------------
__global__ __launch_bounds__(256) void norm_kernel(float* __restrict__ out,
                                                   const float* __restrict__ ss) {
    int i = blockIdx.x * 256 + threadIdx.x;
    float4 v = ((float4*)out)[i];
    int oc = (i >> 8) & 63;
    float sc = ss[oc];
    float sh = ss[64 + oc];
    v.x = fminf(1.0f, fmaxf(-1.0f, fmaf(v.x, sc, sh)));
    v.y = fminf(1.0f, fmaxf(-1.0f, fmaf(v.y, sc, sh)));
    v.z = fminf(1.0f, fmaxf(-1.0f, fmaf(v.z, sc, sh)));
    v.w = fminf(1.0f, fmaxf(-1.0f, fmaf(v.w, sc, sh)));
    ((float4*)out)[i] = v;
}

// ---------------------------------------------------------------------------
extern "C" void kernel_launch(void* const* d_in, const int* in_sizes, int n_in,
                              void* d_out, int out_size, void* d_ws, size_t ws_size,
                              hipStream_t stream) {
    const float* x     = (const float*)d_in[0];
    const float* w     = (const float*)d_in[1];
    const float* gamma = (const float*)d_in[2];
    const float* beta  = (const float*)d_in[3];
    float* out = (float*)d_out;

    char*  wfrag    = (char*)d_ws;                          // 147456 B
    float* partials = (float*)((char*)d_ws + 147456);       // 128*1024 floats
    float* ss       = partials + 128 * NBLK;                // 128 floats

    hipLaunchKernelGGL(prep_kernel, dim3(144), dim3(256), 0, stream, w, wfrag);
    hipLaunchKernelGGL(conv_kernel, dim3(16, 64), dim3(256), 0, stream, x, wfrag, out, partials);
    hipLaunchKernelGGL(stats_kernel, dim3(64), dim3(512), 0, stream, partials, gamma, beta, ss);
    hipLaunchKernelGGL(norm_kernel, dim3(4096), dim3(256), 0, stream, out, ss);
}